// Round 1
// baseline (385.789 us; speedup 1.0000x reference)
//
#include <hip/hip_runtime.h>
#include <hip/hip_bf16.h>

// Problem constants (from setup_inputs)
#define N_TOT 32768
#define G 4
#define DIM 128
#define CB 512

// Tiling
#define BM 64        // rows (n) per block
#define BN 64        // codebook entries per chunk
#define NCHUNK (CB / BN)
#define STR 129      // LDS row stride in floats (odd -> <=2-way bank aliasing)

// Output layout (floats)
#define XHAT_OFF   0
#define ONEHOT_OFF ((size_t)N_TOT * G * DIM)                      // 16777216
#define IDX_OFF    (ONEHOT_OFF + (size_t)N_TOT * G * CB)          // 83886080

// ---------------------------------------------------------------------------
// Kernel 0: cb2h[g*CB + k] = 0.5 * sum_d cb[g][k][d]^2
// ---------------------------------------------------------------------------
__global__ void cvq_cb2_kernel(const float* __restrict__ cb, float* __restrict__ cb2h) {
    int i = blockIdx.x * 256 + threadIdx.x;   // 0 .. G*CB-1 = 2047
    if (i >= G * CB) return;
    const float4* p = (const float4*)&cb[(size_t)i * DIM];
    float s = 0.f;
#pragma unroll
    for (int j = 0; j < DIM / 4; ++j) {
        float4 v = p[j];
        s += v.x * v.x + v.y * v.y + v.z * v.z + v.w * v.w;
    }
    cb2h[i] = 0.5f * s;
}

// ---------------------------------------------------------------------------
// Main kernel: per block = (64 n-rows, one group g)
//   score[n,k] = 0.5*cb2[k] - sum_d cb[g,k,d]*x[n,g,d]   (argmin == ref argmin)
//   writes index (as float), x_hat rows, full one_hot rows.
// ---------------------------------------------------------------------------
__global__ __launch_bounds__(256) void cvq_main_kernel(
        const float* __restrict__ x,
        const float* __restrict__ cb,
        const float* __restrict__ cb2h,
        float* __restrict__ out) {

    __shared__ float xs[BM * STR];
    __shared__ float bs[BN * STR];
    __shared__ int   idxs[BM];

    const int n0  = blockIdx.x * BM;
    const int g   = blockIdx.y;
    const int tid = threadIdx.x;
    const int tx  = tid & 15;   // col group (codebook entries)
    const int ty  = tid >> 4;   // row group (n rows)

    // ---- stage x tile: rows n0..n0+63, 128 floats each (coalesced float4) ----
#pragma unroll
    for (int p = 0; p < 8; ++p) {
        int t  = tid + p * 256;          // 0..2047 = 64 rows * 32 float4
        int r  = t >> 5;
        int d4 = (t & 31) << 2;
        float4 v = *(const float4*)&x[(((size_t)(n0 + r)) * G + g) * DIM + d4];
        float* dst = &xs[r * STR + d4];
        dst[0] = v.x; dst[1] = v.y; dst[2] = v.z; dst[3] = v.w;
    }

    float bestv[4] = {3.0e38f, 3.0e38f, 3.0e38f, 3.0e38f};
    int   besti[4] = {0, 0, 0, 0};

    for (int c = 0; c < NCHUNK; ++c) {
        __syncthreads();   // previous chunk's readers done before overwriting bs
        // ---- stage codebook chunk: entries c*64 .. c*64+63 ----
#pragma unroll
        for (int p = 0; p < 8; ++p) {
            int t  = tid + p * 256;
            int r  = t >> 5;
            int d4 = (t & 31) << 2;
            float4 v = *(const float4*)&cb[((size_t)g * CB + c * BN + r) * DIM + d4];
            float* dst = &bs[r * STR + d4];
            dst[0] = v.x; dst[1] = v.y; dst[2] = v.z; dst[3] = v.w;
        }
        __syncthreads();

        // ---- 64x64 cross-product tile, 4x4 per thread ----
        float acc[4][4];
#pragma unroll
        for (int i = 0; i < 4; ++i)
#pragma unroll
            for (int j = 0; j < 4; ++j) acc[i][j] = 0.f;

        const float* xrow = &xs[(4 * ty) * STR];
        const float* brow = &bs[(4 * tx) * STR];
#pragma unroll 4
        for (int d = 0; d < DIM; ++d) {
            float a0 = xrow[0 * STR + d];
            float a1 = xrow[1 * STR + d];
            float a2 = xrow[2 * STR + d];
            float a3 = xrow[3 * STR + d];
            float b0 = brow[0 * STR + d];
            float b1 = brow[1 * STR + d];
            float b2 = brow[2 * STR + d];
            float b3 = brow[3 * STR + d];
            acc[0][0] += a0 * b0; acc[0][1] += a0 * b1; acc[0][2] += a0 * b2; acc[0][3] += a0 * b3;
            acc[1][0] += a1 * b0; acc[1][1] += a1 * b1; acc[1][2] += a1 * b2; acc[1][3] += a1 * b3;
            acc[2][0] += a2 * b0; acc[2][1] += a2 * b1; acc[2][2] += a2 * b2; acc[2][3] += a2 * b3;
            acc[3][0] += a3 * b0; acc[3][1] += a3 * b1; acc[3][2] += a3 * b2; acc[3][3] += a3 * b3;
        }

        // ---- fold into per-thread running best (k ascending -> first-min ties) ----
#pragma unroll
        for (int j = 0; j < 4; ++j) {
            int   k  = c * BN + 4 * tx + j;
            float c2 = cb2h[g * CB + k];
#pragma unroll
            for (int i = 0; i < 4; ++i) {
                float sc = c2 - acc[i][j];
                if (sc < bestv[i]) { bestv[i] = sc; besti[i] = k; }
            }
        }
    }

    // ---- reduce across the 16 tx-threads sharing each row group (in-wave) ----
#pragma unroll
    for (int off = 1; off < 16; off <<= 1) {
#pragma unroll
        for (int i = 0; i < 4; ++i) {
            float ov = __shfl_xor(bestv[i], off);
            int   oi = __shfl_xor(besti[i], off);
            if (ov < bestv[i] || (ov == bestv[i] && oi < besti[i])) {
                bestv[i] = ov; besti[i] = oi;
            }
        }
    }
    if (tx == 0) {
#pragma unroll
        for (int i = 0; i < 4; ++i) idxs[4 * ty + i] = besti[i];
    }
    __syncthreads();

    float* out_xhat = out + XHAT_OFF;
    float* out_oh   = out + ONEHOT_OFF;
    float* out_idx  = out + IDX_OFF;

    // ---- index output (as float) ----
    if (tid < BM) {
        out_idx[(size_t)(n0 + tid) * G + g] = (float)idxs[tid];
    }

    // ---- x_hat: gather codebook rows (codebook is L2-resident) ----
#pragma unroll
    for (int p = 0; p < 8; ++p) {
        int t  = tid + p * 256;
        int r  = t >> 5;
        int d4 = (t & 31) << 2;
        int k  = idxs[r];
        float4 v = *(const float4*)&cb[((size_t)g * CB + k) * DIM + d4];
        *(float4*)&out_xhat[(((size_t)(n0 + r)) * G + g) * DIM + d4] = v;
    }

    // ---- one_hot: 64 rows x 512 floats, written in full (fused zero-fill) ----
#pragma unroll
    for (int p = 0; p < 32; ++p) {
        int t  = tid + p * 256;
        int r  = t >> 7;          // 128 float4 per row
        int k4 = (t & 127) << 2;
        int k  = idxs[r];
        float4 v;
        v.x = (k4 + 0 == k) ? 1.f : 0.f;
        v.y = (k4 + 1 == k) ? 1.f : 0.f;
        v.z = (k4 + 2 == k) ? 1.f : 0.f;
        v.w = (k4 + 3 == k) ? 1.f : 0.f;
        *(float4*)&out_oh[(((size_t)(n0 + r)) * G + g) * CB + k4] = v;
    }
}

extern "C" void kernel_launch(void* const* d_in, const int* in_sizes, int n_in,
                              void* d_out, int out_size, void* d_ws, size_t ws_size,
                              hipStream_t stream) {
    const float* x  = (const float*)d_in[0];
    const float* cb = (const float*)d_in[1];
    float* out  = (float*)d_out;
    float* cb2h = (float*)d_ws;     // G*CB floats = 8 KB scratch

    cvq_cb2_kernel<<<dim3((G * CB + 255) / 256), dim3(256), 0, stream>>>(cb, cb2h);
    cvq_main_kernel<<<dim3(N_TOT / BM, G), dim3(256), 0, stream>>>(x, cb, cb2h, out);
}

// Round 2
// 331.569 us; speedup vs baseline: 1.1635x; 1.1635x over previous
//
#include <hip/hip_runtime.h>
#include <hip/hip_bf16.h>

// Problem constants (from setup_inputs)
#define N_TOT 32768
#define G 4
#define DIM 128
#define CB 512

// Tiling
#define BM 64        // rows (n) per block
#define BN 64        // codebook entries per chunk
#define NCHUNK (CB / BN)

// Output layout (floats)
#define XHAT_OFF   0
#define ONEHOT_OFF ((size_t)N_TOT * G * DIM)                      // 16777216
#define IDX_OFF    (ONEHOT_OFF + (size_t)N_TOT * G * CB)          // 83886080

// float4-chunk XOR swizzle within a 128-float row: chunk c of row r lives at
// float offset 4*(c ^ ((r>>2)&7)). Keeps b128 alignment, spreads the
// 16-distinct-row B-reads across all 8 bank-quads (2-way max), staging
// writes remain a permutation of a conflict-free linear pattern.
__device__ __forceinline__ int swz(int r, int c) { return (c ^ ((r >> 2) & 7)) << 2; }

// ---------------------------------------------------------------------------
// Kernel 0: cb2h[g*CB + k] = 0.5 * sum_d cb[g][k][d]^2
// ---------------------------------------------------------------------------
__global__ void cvq_cb2_kernel(const float* __restrict__ cb, float* __restrict__ cb2h) {
    int i = blockIdx.x * 256 + threadIdx.x;   // 0 .. G*CB-1 = 2047
    if (i >= G * CB) return;
    const float4* p = (const float4*)&cb[(size_t)i * DIM];
    float s = 0.f;
#pragma unroll
    for (int j = 0; j < DIM / 4; ++j) {
        float4 v = p[j];
        s += v.x * v.x + v.y * v.y + v.z * v.z + v.w * v.w;
    }
    cb2h[i] = 0.5f * s;
}

// ---------------------------------------------------------------------------
// Main kernel: per block = (64 n-rows, one group g)
//   score[n,k] = 0.5*cb2[k] - sum_d cb[g,k,d]*x[n,g,d]   (argmin == ref argmin)
//   writes index (as float), x_hat rows, full one_hot rows.
// ---------------------------------------------------------------------------
__global__ __launch_bounds__(256) void cvq_main_kernel(
        const float* __restrict__ x,
        const float* __restrict__ cb,
        const float* __restrict__ cb2h,
        float* __restrict__ out) {

    __shared__ float xs[BM * DIM];   // 32 KB, swizzled chunks
    __shared__ float bs[BN * DIM];   // 32 KB, swizzled chunks
    __shared__ int   idxs[BM];

    const int n0  = blockIdx.x * BM;
    const int g   = blockIdx.y;
    const int tid = threadIdx.x;
    const int tx  = tid & 15;   // col group (codebook entries)
    const int ty  = tid >> 4;   // row group (n rows)

    // ---- stage x tile: rows n0..n0+63, 128 floats each (coalesced float4) ----
#pragma unroll
    for (int p = 0; p < 8; ++p) {
        int t = tid + p * 256;           // 0..2047 = 64 rows * 32 chunks
        int r = t >> 5;
        int c = t & 31;
        float4 v = *(const float4*)&x[(((size_t)(n0 + r)) * G + g) * DIM + (c << 2)];
        *(float4*)&xs[r * DIM + swz(r, c)] = v;
    }

    float bestv[4] = {3.0e38f, 3.0e38f, 3.0e38f, 3.0e38f};
    int   besti[4] = {0, 0, 0, 0};

    const int sa = ty & 7;
    const int sb = tx & 7;

    for (int ch = 0; ch < NCHUNK; ++ch) {
        __syncthreads();   // previous chunk's readers done before overwriting bs
        // ---- stage codebook chunk: entries ch*64 .. ch*64+63 ----
#pragma unroll
        for (int p = 0; p < 8; ++p) {
            int t = tid + p * 256;
            int r = t >> 5;
            int c = t & 31;
            float4 v = *(const float4*)&cb[((size_t)g * CB + ch * BN + r) * DIM + (c << 2)];
            *(float4*)&bs[r * DIM + swz(r, c)] = v;
        }
        __syncthreads();

        // ---- 64x64 cross-product tile, 4x4 per thread, float4 LDS reads ----
        float acc[4][4];
#pragma unroll
        for (int i = 0; i < 4; ++i)
#pragma unroll
            for (int j = 0; j < 4; ++j) acc[i][j] = 0.f;

#pragma unroll 8
        for (int c = 0; c < 32; ++c) {
            const int oa = ((c ^ sa) << 2);
            const int ob = ((c ^ sb) << 2);
            float4 a[4], b[4];
#pragma unroll
            for (int i = 0; i < 4; ++i) a[i] = *(const float4*)&xs[(4 * ty + i) * DIM + oa];
#pragma unroll
            for (int j = 0; j < 4; ++j) b[j] = *(const float4*)&bs[(4 * tx + j) * DIM + ob];
#pragma unroll
            for (int i = 0; i < 4; ++i)
#pragma unroll
                for (int j = 0; j < 4; ++j) {
                    acc[i][j] = fmaf(a[i].x, b[j].x,
                                fmaf(a[i].y, b[j].y,
                                fmaf(a[i].z, b[j].z,
                                fmaf(a[i].w, b[j].w, acc[i][j]))));
                }
        }

        // ---- fold into per-thread running best (k ascending -> first-min ties) ----
#pragma unroll
        for (int j = 0; j < 4; ++j) {
            int   k  = ch * BN + 4 * tx + j;
            float c2 = cb2h[g * CB + k];
#pragma unroll
            for (int i = 0; i < 4; ++i) {
                float sc = c2 - acc[i][j];
                if (sc < bestv[i]) { bestv[i] = sc; besti[i] = k; }
            }
        }
    }

    // ---- reduce across the 16 tx-threads sharing each row group (in-wave) ----
#pragma unroll
    for (int off = 1; off < 16; off <<= 1) {
#pragma unroll
        for (int i = 0; i < 4; ++i) {
            float ov = __shfl_xor(bestv[i], off);
            int   oi = __shfl_xor(besti[i], off);
            if (ov < bestv[i] || (ov == bestv[i] && oi < besti[i])) {
                bestv[i] = ov; besti[i] = oi;
            }
        }
    }
    if (tx == 0) {
#pragma unroll
        for (int i = 0; i < 4; ++i) idxs[4 * ty + i] = besti[i];
    }
    __syncthreads();

    float* out_xhat = out + XHAT_OFF;
    float* out_oh   = out + ONEHOT_OFF;
    float* out_idx  = out + IDX_OFF;

    // ---- index output (as float) ----
    if (tid < BM) {
        out_idx[(size_t)(n0 + tid) * G + g] = (float)idxs[tid];
    }

    // ---- x_hat: gather codebook rows (codebook is L2-resident) ----
#pragma unroll
    for (int p = 0; p < 8; ++p) {
        int t  = tid + p * 256;
        int r  = t >> 5;
        int d4 = (t & 31) << 2;
        int k  = idxs[r];
        float4 v = *(const float4*)&cb[((size_t)g * CB + k) * DIM + d4];
        *(float4*)&out_xhat[(((size_t)(n0 + r)) * G + g) * DIM + d4] = v;
    }

    // ---- one_hot: 64 rows x 512 floats, written in full (fused zero-fill) ----
#pragma unroll
    for (int p = 0; p < 32; ++p) {
        int t  = tid + p * 256;
        int r  = t >> 7;          // 128 float4 per row
        int k4 = (t & 127) << 2;
        int k  = idxs[r];
        float4 v;
        v.x = (k4 + 0 == k) ? 1.f : 0.f;
        v.y = (k4 + 1 == k) ? 1.f : 0.f;
        v.z = (k4 + 2 == k) ? 1.f : 0.f;
        v.w = (k4 + 3 == k) ? 1.f : 0.f;
        *(float4*)&out_oh[(((size_t)(n0 + r)) * G + g) * CB + k4] = v;
    }
}

extern "C" void kernel_launch(void* const* d_in, const int* in_sizes, int n_in,
                              void* d_out, int out_size, void* d_ws, size_t ws_size,
                              hipStream_t stream) {
    const float* x  = (const float*)d_in[0];
    const float* cb = (const float*)d_in[1];
    float* out  = (float*)d_out;
    float* cb2h = (float*)d_ws;     // G*CB floats = 8 KB scratch

    cvq_cb2_kernel<<<dim3((G * CB + 255) / 256), dim3(256), 0, stream>>>(cb, cb2h);
    cvq_main_kernel<<<dim3(N_TOT / BM, G), dim3(256), 0, stream>>>(x, cb, cb2h, out);
}

// Round 4
// 208.781 us; speedup vs baseline: 1.8478x; 1.5881x over previous
//
#include <hip/hip_runtime.h>
#include <hip/hip_bf16.h>

// Problem constants
#define N_TOT 32768
#define G 4
#define DIM 128
#define CB 512
#define BM 64            // rows per block; 4 waves x 128 cols = full CB per block

// Output layout (floats)
#define XHAT_OFF   0
#define ONEHOT_OFF ((size_t)N_TOT * G * DIM)                      // 16777216
#define IDX_OFF    (ONEHOT_OFF + (size_t)N_TOT * G * CB)          // 83886080

typedef _Float16 half8    __attribute__((ext_vector_type(8)));
typedef float    floatx16 __attribute__((ext_vector_type(16)));
typedef float    floatx4  __attribute__((ext_vector_type(4)));   // clang vector: ok for nontemporal builtins

// ---------------------------------------------------------------------------
// Kernel 0: cb2h[g*CB + k] = 0.5 * sum_d cb[g][k][d]^2   (unchanged, validated)
// ---------------------------------------------------------------------------
__global__ void cvq_cb2_kernel(const float* __restrict__ cb, float* __restrict__ cb2h) {
    int i = blockIdx.x * 256 + threadIdx.x;   // 0 .. G*CB-1 = 2047
    if (i >= G * CB) return;
    const float4* p = (const float4*)&cb[(size_t)i * DIM];
    float s = 0.f;
#pragma unroll
    for (int j = 0; j < DIM / 4; ++j) {
        float4 v = p[j];
        s += v.x * v.x + v.y * v.y + v.z * v.z + v.w * v.w;
    }
    cb2h[i] = 0.5f * s;
}

// fp32 -> (hi, lo) fp16 RN split of 8 consecutive values.
// f = hi + lo + err, |err| <= 2^-22 |f|  (Markidis split; lo.lo term omitted
// in the 3-MFMA product is <= 2^-22 |ab| per term -> dot error ~3e-6,
// below the fp32 reorder noise that already gave absmax 0.0).
__device__ __forceinline__ void split8(floatx4 v0, floatx4 v1, half8& hi, half8& lo) {
    float f[8] = {v0.x, v0.y, v0.z, v0.w, v1.x, v1.y, v1.z, v1.w};
#pragma unroll
    for (int e = 0; e < 8; ++e) {
        _Float16 h = (_Float16)f[e];           // RN
        hi[e] = h;
        lo[e] = (_Float16)(f[e] - (float)h);   // exact residual, then RN
    }
}

// ---------------------------------------------------------------------------
// Main kernel: block = (64 n-rows, one group g), 4 waves.
// Wave w computes cross[64 x 128] for cols w*128.. via v_mfma_f32_32x32x16_f16
// with fp16x3 split (fp32-quality). score = 0.5*cb2[k] - cross  (same argmin
// as reference dist). Then per-row argmin, idx/x_hat/one_hot epilogue.
//
// Fragment layouts (gfx950 32x32x16):
//   A: lane l, elem e:  row = l&31,  k = (l>>5)*8 + e
//   B: lane l, elem e:  col = l&31,  k = (l>>5)*8 + e
//   C: lane l, reg r:   col = l&31,  row = (r&3) + 8*(r>>2) + 4*(l>>5)   [m74/m101]
// ---------------------------------------------------------------------------
__global__ __launch_bounds__(256, 2) void cvq_main_kernel(
        const float* __restrict__ x,
        const float* __restrict__ cb,
        const float* __restrict__ cb2h,
        float* __restrict__ out) {

    __shared__ float part_v[4][BM];
    __shared__ int   part_i[4][BM];
    __shared__ int   idxs[BM];

    const int n0   = blockIdx.x * BM;
    const int g    = blockIdx.y;
    const int tid  = threadIdx.x;
    const int wid  = tid >> 6;        // wave 0..3 -> cols wid*128..+127
    const int lane = tid & 63;
    const int col  = lane & 31;
    const int h    = lane >> 5;
    const int klo  = h * 8;           // k-offset within a 16-wide K step

    // Per-lane source rows (A: x rows; B: codebook entries), at k-offset klo
    const float* xr0 = &x[(((size_t)(n0 + col)) * G + g) * DIM + klo];
    const float* xr1 = &x[(((size_t)(n0 + 32 + col)) * G + g) * DIM + klo];
    const float* cbr[4];
#pragma unroll
    for (int t = 0; t < 4; ++t)
        cbr[t] = &cb[((size_t)g * CB + wid * 128 + t * 32 + col) * DIM + klo];

    floatx16 acc[2][4] = {};   // [mtile][ntile], fp32 accumulators = cross

#pragma unroll
    for (int ks = 0; ks < 8; ++ks) {
        const int d = ks * 16;
        half8 ah[2], al[2];
        split8(*(const floatx4*)(xr0 + d), *(const floatx4*)(xr0 + d + 4), ah[0], al[0]);
        split8(*(const floatx4*)(xr1 + d), *(const floatx4*)(xr1 + d + 4), ah[1], al[1]);
#pragma unroll
        for (int t = 0; t < 4; ++t) {
            half8 bh, bl;
            split8(*(const floatx4*)(cbr[t] + d), *(const floatx4*)(cbr[t] + d + 4), bh, bl);
#pragma unroll
            for (int mt = 0; mt < 2; ++mt) {
                acc[mt][t] = __builtin_amdgcn_mfma_f32_32x32x16_f16(ah[mt], bh, acc[mt][t], 0, 0, 0);
                acc[mt][t] = __builtin_amdgcn_mfma_f32_32x32x16_f16(ah[mt], bl, acc[mt][t], 0, 0, 0);
                acc[mt][t] = __builtin_amdgcn_mfma_f32_32x32x16_f16(al[mt], bh, acc[mt][t], 0, 0, 0);
            }
        }
    }

    // ---- per-row argmin over this wave's 128 cols ----
    float c2v[4];
#pragma unroll
    for (int t = 0; t < 4; ++t)
        c2v[t] = cb2h[g * CB + wid * 128 + t * 32 + col];

#pragma unroll
    for (int mt = 0; mt < 2; ++mt) {
#pragma unroll
        for (int r = 0; r < 16; ++r) {
            const int row = mt * 32 + (r & 3) + 8 * (r >> 2) + 4 * h;   // 0..63
            float bv = c2v[0] - acc[mt][0][r];
            int   bi = wid * 128 + col;
#pragma unroll
            for (int t = 1; t < 4; ++t) {
                float sc = c2v[t] - acc[mt][t][r];
                int   kk = wid * 128 + t * 32 + col;
                if (sc < bv) { bv = sc; bi = kk; }       // k ascending in t
            }
            // reduce over the 32 cols (lanes of this half), first-min ties
#pragma unroll
            for (int off = 1; off < 32; off <<= 1) {
                float ov = __shfl_xor(bv, off);
                int   oi = __shfl_xor(bi, off);
                if (ov < bv || (ov == bv && oi < bi)) { bv = ov; bi = oi; }
            }
            if (col == 0) { part_v[wid][row] = bv; part_i[wid][row] = bi; }
        }
    }
    __syncthreads();

    // ---- combine the 4 waves' col-slices (ascending wave = ascending k) ----
    if (tid < BM) {
        float bv = part_v[0][tid];
        int   bi = part_i[0][tid];
#pragma unroll
        for (int w = 1; w < 4; ++w) {
            float pv = part_v[w][tid];
            int   pi = part_i[w][tid];
            if (pv < bv || (pv == bv && pi < bi)) { bv = pv; bi = pi; }
        }
        idxs[tid] = bi;
        out[IDX_OFF + (size_t)(n0 + tid) * G + g] = (float)bi;
    }
    __syncthreads();

    float* out_xhat = out + XHAT_OFF;
    float* out_oh   = out + ONEHOT_OFF;

    // ---- x_hat: gather codebook rows (L2-resident) ----
#pragma unroll
    for (int p = 0; p < 8; ++p) {
        int t  = tid + p * 256;
        int r  = t >> 5;
        int d4 = (t & 31) << 2;
        int k  = idxs[r];
        floatx4 v = *(const floatx4*)&cb[((size_t)g * CB + k) * DIM + d4];
        __builtin_nontemporal_store(v, (floatx4*)&out_xhat[(((size_t)(n0 + r)) * G + g) * DIM + d4]);
    }

    // ---- one_hot: 64 rows x 512 floats, fused zero-fill, streaming stores ----
#pragma unroll
    for (int p = 0; p < 32; ++p) {
        int t  = tid + p * 256;
        int r  = t >> 7;          // 128 float4 per row
        int k4 = (t & 127) << 2;
        int k  = idxs[r];
        floatx4 v;
        v.x = (k4 + 0 == k) ? 1.f : 0.f;
        v.y = (k4 + 1 == k) ? 1.f : 0.f;
        v.z = (k4 + 2 == k) ? 1.f : 0.f;
        v.w = (k4 + 3 == k) ? 1.f : 0.f;
        __builtin_nontemporal_store(v, (floatx4*)&out_oh[(((size_t)(n0 + r)) * G + g) * CB + k4]);
    }
}

extern "C" void kernel_launch(void* const* d_in, const int* in_sizes, int n_in,
                              void* d_out, int out_size, void* d_ws, size_t ws_size,
                              hipStream_t stream) {
    const float* x  = (const float*)d_in[0];
    const float* cb = (const float*)d_in[1];
    float* out  = (float*)d_out;
    float* cb2h = (float*)d_ws;     // G*CB floats = 8 KB scratch

    cvq_cb2_kernel<<<dim3((G * CB + 255) / 256), dim3(256), 0, stream>>>(cb, cb2h);
    cvq_main_kernel<<<dim3(N_TOT / BM, G), dim3(256), 0, stream>>>(x, cb, cb2h, out);
}